// Round 2
// 536.359 us; speedup vs baseline: 1.0298x; 1.0298x over previous
//
#include <hip/hip_runtime.h>
#include <hip/hip_bf16.h>

// Int8 blockwise-dequant linear: out[m,n] = sum_k x[m,k]*(qw[n,k]*scale[(n*4096+k)/64]) + bias[n]
// M=8192, N=4096, K=4096.
//
// R5 = R4 hardened (R4 never ran: container failure, possible GPU hang):
//   - rule #18 fix: __builtin_amdgcn_sched_barrier(0) after EVERY inline-asm s_waitcnt
//     (hipcc may hoist ops past asm waitcnt despite "memory" clobber)
//   - rule #20 fix: 3-buffer LDS ring now uses COMPILE-TIME buffer indices
//     (main loop unrolled x3; NT-2 = 126 = 3*42), no runtime ring counters
// Schedule (unchanged from R4): T3+T4+T5 counted-vmcnt structure:
//   - 256x256 tile, BK=32, 8 waves (2Mx4N), 512 threads, 96 KiB LDS (3-buffer ring)
//   - prefetch distance 2: tile t stages tile t+2 into buf[(t+2)%3], which was last
//     read at tile t-1 and released at its end-of-tile barrier -> race-free
//   - ONE counted s_waitcnt vmcnt(4) per K-tile (never 0 in main loop): tile t+1's
//     4 loads proven done, tile t+2's 4 loads stay in flight ACROSS the barrier
//   - raw s_barrier + s_setprio(1) around each 16-MFMA cluster (2 phases/tile)
//   - BK=32 row stride = 64 B puts a row bit into LDS addr bit 6 -> ds_read_b128
//     groups spread across bank-groups (<=2-way aliasing, free per m136); no swizzle
//     needed, so linear global_load_lds staging stays legal.

using bf16x8 = __attribute__((ext_vector_type(8))) short;  // MFMA A/B frag (4 VGPRs)
using f32x4  = __attribute__((ext_vector_type(4))) float;  // MFMA C/D frag

constexpr int Mtot = 8192, Ntot = 4096, Ktot = 4096;

__device__ __forceinline__ short f2bf(float f) {
    __hip_bfloat16 h = __float2bfloat16(f);
    return *reinterpret_cast<short*>(&h);
}

#define GLD_LDS16(gp, lp)                                             \
    __builtin_amdgcn_global_load_lds(                                 \
        (const __attribute__((address_space(1))) void*)(gp),          \
        (__attribute__((address_space(3))) void*)(lp), 16, 0, 0)

// counted vmcnt + mandatory post-fence (rule #18)
#define WAITV(n)                                                      \
    do { asm volatile("s_waitcnt vmcnt(" #n ")" ::: "memory");        \
         __builtin_amdgcn_sched_barrier(0); } while (0)

// ---------------- fused pre-pass: X->bf16 and W-dequant->bf16 in one dispatch ----------------
__global__ __launch_bounds__(256)
void prep_bf16(const float* __restrict__ X, short* __restrict__ Xb, int xblocks,
               const int* __restrict__ Wq, const float* __restrict__ scales,
               short* __restrict__ Wb)
{
    const int b = blockIdx.x;
    if (b < xblocks) {
        const int i = (b * 256 + threadIdx.x) * 8;
        const float4 a = *reinterpret_cast<const float4*>(X + i);
        const float4 c = *reinterpret_cast<const float4*>(X + i + 4);
        bf16x8 h;
        h[0] = f2bf(a.x); h[1] = f2bf(a.y); h[2] = f2bf(a.z); h[3] = f2bf(a.w);
        h[4] = f2bf(c.x); h[5] = f2bf(c.y); h[6] = f2bf(c.z); h[7] = f2bf(c.w);
        *reinterpret_cast<bf16x8*>(Xb + i) = h;
    } else {
        const int i = ((b - xblocks) * 256 + threadIdx.x) * 8;
        const float s = scales[i >> 6];  // 8 consecutive elems share one 64-block
        const int4 a = *reinterpret_cast<const int4*>(Wq + i);
        const int4 c = *reinterpret_cast<const int4*>(Wq + i + 4);
        bf16x8 h;
        h[0] = f2bf((float)a.x * s); h[1] = f2bf((float)a.y * s);
        h[2] = f2bf((float)a.z * s); h[3] = f2bf((float)a.w * s);
        h[4] = f2bf((float)c.x * s); h[5] = f2bf((float)c.y * s);
        h[6] = f2bf((float)c.z * s); h[7] = f2bf((float)c.w * s);
        *reinterpret_cast<bf16x8*>(Wb + i) = h;
    }
}

// ---------------- 256x256 counted-vmcnt GEMM (A[M,K] x B[N,K]^T) ----------------
constexpr int BM = 256, BN = 256, BK = 32;
constexpr int NT = Ktot / BK;            // 128 K-tiles
constexpr int TS = BM * BK;              // 8192 shorts per buffer (16 KiB)

__global__ __launch_bounds__(512, 2)
void gemm_bf16_256(const short* __restrict__ A, const short* __restrict__ B,
                   const float* __restrict__ bias, float* __restrict__ Out)
{
    __shared__ __align__(16) short As[3][TS];  // 48 KiB
    __shared__ __align__(16) short Bs[3][TS];  // 48 KiB

    const int tid  = threadIdx.x;
    const int wave = tid >> 6, lane = tid & 63;
    const int bm0 = blockIdx.y * BM, bn0 = blockIdx.x * BN;
    const int wm = (wave >> 2) * 128;        // 2 M-groups of waves
    const int wn = (wave & 3) * 64;          // 4 N-groups of waves
    const int lrow = lane & 15, lquad = lane >> 4;

    // DMA staging: instruction j of wave w covers tile rows [(w*2+j)*16, +16);
    // lane l -> row +(l>>2), k-elems (l&3)*8. LDS dest = wave-uniform base + lane*16 B,
    // which equals row-major [row][k] exactly: lw + l*8 shorts = (w*32+(l>>2))*32+(l&3)*8.
    const int srow = lane >> 2, sk = (lane & 3) * 8;
    const int r0 = (wave * 2) * 16 + srow;
    const short* Ag0 = A + (size_t)(bm0 + r0) * Ktot + sk;
    const short* Ag1 = Ag0 + (size_t)16 * Ktot;
    const short* Bg0 = B + (size_t)(bn0 + r0) * Ktot + sk;
    const short* Bg1 = Bg0 + (size_t)16 * Ktot;
    const int lw = wave * 1024;              // LDS write offset in shorts (2048 B/wave)

    f32x4 acc[8][4] = {};

#define STAGE_A(bufs, koff)                                   \
    do { GLD_LDS16(Ag0 + (koff), &As[bufs][lw]);              \
         GLD_LDS16(Ag1 + (koff), &As[bufs][lw + 512]); } while (0)
#define STAGE_B(bufs, koff)                                   \
    do { GLD_LDS16(Bg0 + (koff), &Bs[bufs][lw]);              \
         GLD_LDS16(Bg1 + (koff), &Bs[bufs][lw + 512]); } while (0)

    // prologue: stage tiles 0 and 1; wait tile 0 (4 youngest = tile 1 stay in flight)
    STAGE_A(0, 0);  STAGE_B(0, 0);
    STAGE_A(1, BK); STAGE_B(1, BK);
    WAITV(4);
    __builtin_amdgcn_s_barrier();

    // Per tile: 2 phases x {ds_read subtile | 2 gld_lds | bar | setprio(1) 16 MFMA setprio(0) | bar}
    // vmcnt(4) once per tile, AFTER both staging issues -> tile t+1 proven complete,
    // tile t+2's 4 loads cross the barrier still in flight.
#define TILE_BODY(bufc, DO_STAGE, bufs, koff, WAIT_CODE)                       \
    do {                                                                       \
        const short* ab = &As[bufc][(wm + lrow) * BK + lquad * 8];             \
        const short* bb = &Bs[bufc][(wn + lrow) * BK + lquad * 8];             \
        bf16x8 af[4], bfr[4];                                                  \
        _Pragma("unroll")                                                      \
        for (int i = 0; i < 4; i++)                                            \
            af[i] = *reinterpret_cast<const bf16x8*>(ab + i * 512);            \
        _Pragma("unroll")                                                      \
        for (int n = 0; n < 4; n++)                                            \
            bfr[n] = *reinterpret_cast<const bf16x8*>(bb + n * 512);           \
        if (DO_STAGE) STAGE_A(bufs, koff);                                     \
        __builtin_amdgcn_s_barrier();                                          \
        __builtin_amdgcn_s_setprio(1);                                         \
        _Pragma("unroll")                                                      \
        for (int i = 0; i < 4; i++)                                            \
            _Pragma("unroll")                                                  \
            for (int n = 0; n < 4; n++)                                        \
                acc[i][n] = __builtin_amdgcn_mfma_f32_16x16x32_bf16(           \
                    af[i], bfr[n], acc[i][n], 0, 0, 0);                        \
        __builtin_amdgcn_s_setprio(0);                                         \
        __builtin_amdgcn_s_barrier();                                          \
        _Pragma("unroll")                                                      \
        for (int i = 0; i < 4; i++)                                            \
            af[i] = *reinterpret_cast<const bf16x8*>(ab + 2048 + i * 512);     \
        if (DO_STAGE) STAGE_B(bufs, koff);                                     \
        WAIT_CODE;                                                             \
        __builtin_amdgcn_s_barrier();                                          \
        __builtin_amdgcn_s_setprio(1);                                         \
        _Pragma("unroll")                                                      \
        for (int i = 0; i < 4; i++)                                            \
            _Pragma("unroll")                                                  \
            for (int n = 0; n < 4; n++)                                        \
                acc[4 + i][n] = __builtin_amdgcn_mfma_f32_16x16x32_bf16(       \
                    af[i], bfr[n], acc[4 + i][n], 0, 0, 0);                    \
        __builtin_amdgcn_s_setprio(0);                                         \
        __builtin_amdgcn_s_barrier();                                          \
    } while (0)

    // main loop: 126 tiles = 42 x 3, compile-time ring indices (t%3, (t+2)%3)
    int koff = 2 * BK;
    for (int t = 0; t < NT - 2; t += 3) {
        TILE_BODY(0, true, 2, koff, WAITV(4)); koff += BK;
        TILE_BODY(1, true, 0, koff, WAITV(4)); koff += BK;
        TILE_BODY(2, true, 1, koff, WAITV(4)); koff += BK;
    }
    // tile 126 (buf 0): no staging left; drain last tile's loads (4 -> 0)
    TILE_BODY(0, false, 0, 0, WAITV(0));
    // tile 127 (buf 1): nothing outstanding
    TILE_BODY(1, false, 0, 0, ((void)0));

    // epilogue: C/D layout col=lane&15, row=(lane>>4)*4+reg (verified convention)
    #pragma unroll
    for (int n = 0; n < 4; n++) {
        const int col = bn0 + wn + n * 16 + lrow;
        const float bv = bias[col];
        #pragma unroll
        for (int m = 0; m < 8; m++) {
            const int rowb = bm0 + wm + m * 16 + lquad * 4;
            #pragma unroll
            for (int r = 0; r < 4; r++)
                Out[(size_t)(rowb + r) * Ntot + col] = acc[m][n][r] + bv;
        }
    }
}

// ---------------- R2 fused fallback (ws too small) ----------------
constexpr int BMf = 128, BNf = 128, BKf = 64;
constexpr int LDSS = BKf + 8;
__global__ __launch_bounds__(256, 2)
void int8linear_fused(const float* __restrict__ X, const int* __restrict__ Wq,
                      const float* __restrict__ scales, const float* __restrict__ bias,
                      float* __restrict__ Out)
{
    __shared__ __align__(16) short As[BMf * LDSS];
    __shared__ __align__(16) short Bs[BNf * LDSS];
    const int tid = threadIdx.x;
    const int bm0 = blockIdx.y * BMf, bn0 = blockIdx.x * BNf;
    const int wave = tid >> 6, lane = tid & 63;
    const int wm = (wave & 1) * 64, wn = (wave >> 1) * 64;
    const int lrow = lane & 15, lquad = lane >> 4;
    const int a_kgrp = tid & 15, a_row0 = tid >> 4;
    const int b_row = tid >> 1, b_koff = (tid & 1) * 32;
    f32x4 acc[4][4] = {};
    const float* xbase = X + (size_t)bm0 * Ktot;
    const int*   wbase = Wq + (size_t)(bn0 + b_row) * Ktot + b_koff;
    const float* sbase = scales + (size_t)(bn0 + b_row) * (Ktot / 64);
    for (int k0 = 0; k0 < Ktot; k0 += BKf) {
        #pragma unroll
        for (int rr = 0; rr < 8; rr++) {
            const int row = a_row0 + rr * 16;
            const float4 v = *reinterpret_cast<const float4*>(
                xbase + (size_t)row * Ktot + k0 + a_kgrp * 4);
            short4 h; h.x = f2bf(v.x); h.y = f2bf(v.y); h.z = f2bf(v.z); h.w = f2bf(v.w);
            *reinterpret_cast<short4*>(&As[row * LDSS + a_kgrp * 4]) = h;
        }
        {
            const float s = sbase[k0 >> 6];
            int4 r[8];
            #pragma unroll
            for (int u = 0; u < 8; u++) r[u] = *reinterpret_cast<const int4*>(wbase + k0 + u * 4);
            short* dst = &Bs[b_row * LDSS + b_koff];
            #pragma unroll
            for (int u = 0; u < 8; u++) {
                short4 h;
                h.x = f2bf((float)r[u].x * s); h.y = f2bf((float)r[u].y * s);
                h.z = f2bf((float)r[u].z * s); h.w = f2bf((float)r[u].w * s);
                *reinterpret_cast<short4*>(dst + u * 4) = h;
            }
        }
        __syncthreads();
        #pragma unroll
        for (int ks = 0; ks < 2; ks++) {
            bf16x8 af[4], bfr[4];
            #pragma unroll
            for (int i = 0; i < 4; i++)
                af[i] = *reinterpret_cast<const bf16x8*>(&As[(wm + i*16 + lrow) * LDSS + ks*32 + lquad*8]);
            #pragma unroll
            for (int j = 0; j < 4; j++)
                bfr[j] = *reinterpret_cast<const bf16x8*>(&Bs[(wn + j*16 + lrow) * LDSS + ks*32 + lquad*8]);
            #pragma unroll
            for (int i = 0; i < 4; i++)
                #pragma unroll
                for (int j = 0; j < 4; j++)
                    acc[i][j] = __builtin_amdgcn_mfma_f32_16x16x32_bf16(af[i], bfr[j], acc[i][j], 0, 0, 0);
        }
        __syncthreads();
    }
    #pragma unroll
    for (int j = 0; j < 4; j++) {
        const int col = bn0 + wn + j * 16 + lrow;
        const float bv = bias[col];
        #pragma unroll
        for (int i = 0; i < 4; i++) {
            const int rowb = bm0 + wm + i * 16 + lquad * 4;
            #pragma unroll
            for (int r = 0; r < 4; r++)
                Out[(size_t)(rowb + r) * Ntot + col] = acc[i][j][r] + bv;
        }
    }
}

extern "C" void kernel_launch(void* const* d_in, const int* in_sizes, int n_in,
                              void* d_out, int out_size, void* d_ws, size_t ws_size,
                              hipStream_t stream) {
    const float* X      = (const float*)d_in[0];
    const int*   Wq     = (const int*)d_in[1];
    const float* scales = (const float*)d_in[2];
    const float* bias   = (const float*)d_in[3];
    float*       Out    = (float*)d_out;

    const size_t xN = (size_t)Mtot * Ktot;          // 33,554,432
    const size_t wN = (size_t)Ntot * Ktot;          // 16,777,216
    const size_t need = xN * 2 + wN * 2;            // ~100.7 MB

    if (ws_size >= need) {
        short* Xb = (short*)d_ws;
        short* Wb = Xb + xN;
        const int xblocks = (int)(xN / 8 / 256);    // 16384
        const int wblocks = (int)(wN / 8 / 256);    // 8192
        prep_bf16<<<xblocks + wblocks, 256, 0, stream>>>(X, Xb, xblocks, Wq, scales, Wb);
        dim3 grid(Ntot / BN, Mtot / BM);            // 16 x 32 = 512 blocks, 512 thr
        gemm_bf16_256<<<grid, 512, 0, stream>>>(Xb, Wb, bias, Out);
    } else {
        dim3 grid(Ntot / BNf, Mtot / BMf);          // 32 x 64 = 2048 blocks
        int8linear_fused<<<grid, 256, 0, stream>>>(X, Wq, scales, bias, Out);
    }
}